// Round 2
// baseline (893.293 us; speedup 1.0000x reference)
//
#include <hip/hip_runtime.h>

// ---------------------------------------------------------------------------
// HedgeHog attention distillation map: pred = (fq.fk^T) rownorm, true = softmax(q0.k0^T/8)
// Output [2,2,16,2048,2048] fp32 = 1.07 GiB  ->  HBM-write-bound (~170us floor).
// k_proj: x->q0,k0 (64x64), ->hq,hk (64x64), fq/fk = [exp(h),exp(-h)]; bf16 to ws.
// k_attn (v2): zero-LDS, zero-barrier. Pass1: register row-sums (shfl butterfly).
// Pass2: recompute tiles from L2-resident ws, normalize in-register, stream fp32
// stores directly to HBM. 4 blocks/CU co-resident -> latency hidden, write-bound.
// ---------------------------------------------------------------------------

typedef __attribute__((ext_vector_type(8))) short  bf16x8;
typedef __attribute__((ext_vector_type(4))) float  f32x4;

#define NN 2048
#define DD 64
#define NBH 32

__device__ __forceinline__ float bf2f(unsigned short u) {
  union { unsigned int i; float f; } v; v.i = ((unsigned int)u) << 16; return v.f;
}
__device__ __forceinline__ unsigned short f2bf(float f) {
  union { float f; unsigned int i; } v; v.f = f;
  unsigned int x = v.i;
  return (unsigned short)((x + 0x7FFFu + ((x >> 16) & 1u)) >> 16);  // RNE
}
__device__ __forceinline__ bf16x8 cvt8(const float* __restrict__ p) {
  bf16x8 v;
#pragma unroll
  for (int i = 0; i < 8; i++) v[i] = (short)f2bf(p[i]);
  return v;
}
__device__ __forceinline__ f32x4 mfma16(bf16x8 a, bf16x8 b, f32x4 c) {
  return __builtin_amdgcn_mfma_f32_16x16x32_bf16(a, b, c, 0, 0, 0);
}

// ---------------------------------------------------------------------------
// Kernel 1: projections + hedgehog features. One wave owns 16 rows.
// ---------------------------------------------------------------------------
__device__ __forceinline__ void proj_chain(
    const bf16x8 ax[2],
    const float* __restrict__ W1, const float* __restrict__ b1,
    const float* __restrict__ W2, const float* __restrict__ b2,
    unsigned short* __restrict__ o1w, unsigned short* __restrict__ o2w,
    unsigned short (*Tq)[72], unsigned short (*Tf)[136],
    long r0, int l15, int g, int l)
{
  // ---- first linear: 16x64 output tile, K=64 ----
#pragma unroll
  for (int nt = 0; nt < 4; nt++) {
    f32x4 acc = {0.f, 0.f, 0.f, 0.f};
    acc = mfma16(ax[0], cvt8(W1 + (nt * 16 + l15) * 64 + g * 8), acc);
    acc = mfma16(ax[1], cvt8(W1 + (nt * 16 + l15) * 64 + 32 + g * 8), acc);
    float bv = b1[nt * 16 + l15];
#pragma unroll
    for (int j = 0; j < 4; j++)
      Tq[g * 4 + j][nt * 16 + l15] = f2bf(acc[j] + bv);   // C layout: row=(l>>4)*4+j, col=l&15
  }
#pragma unroll
  for (int i = 0; i < 2; i++) {
    int c = i * 64 + l;
    int r = c >> 3, cc = c & 7;
    *(bf16x8*)(o1w + (r0 + r) * 64 + cc * 8) = *(const bf16x8*)&Tq[r][cc * 8];
  }
  bf16x8 a1[2];
#pragma unroll
  for (int kk = 0; kk < 2; kk++)
    a1[kk] = *(const bf16x8*)&Tq[l15][kk * 32 + g * 8];
  // ---- second linear + hedgehog exp ----
#pragma unroll
  for (int nt = 0; nt < 4; nt++) {
    f32x4 acc = {0.f, 0.f, 0.f, 0.f};
    acc = mfma16(a1[0], cvt8(W2 + (nt * 16 + l15) * 64 + g * 8), acc);
    acc = mfma16(a1[1], cvt8(W2 + (nt * 16 + l15) * 64 + 32 + g * 8), acc);
    float bv = b2[nt * 16 + l15];
#pragma unroll
    for (int j = 0; j < 4; j++) {
      float h = acc[j] + bv;
      Tf[g * 4 + j][nt * 16 + l15]      = f2bf(__expf(h));
      Tf[g * 4 + j][64 + nt * 16 + l15] = f2bf(__expf(-h));
    }
  }
#pragma unroll
  for (int i = 0; i < 4; i++) {
    int c = i * 64 + l;
    int r = c >> 4, cc = c & 15;
    *(bf16x8*)(o2w + (r0 + r) * 128 + cc * 8) = *(const bf16x8*)&Tf[r][cc * 8];
  }
}

__global__ __launch_bounds__(256) void k_proj(
    const float* __restrict__ x,
    const float* __restrict__ Wq,  const float* __restrict__ bq,
    const float* __restrict__ Wk,  const float* __restrict__ bk,
    const float* __restrict__ Wmq, const float* __restrict__ bmq,
    const float* __restrict__ Wmk, const float* __restrict__ bmk,
    unsigned short* __restrict__ q0w, unsigned short* __restrict__ k0w,
    unsigned short* __restrict__ fqw, unsigned short* __restrict__ fkw)
{
  const int tid = threadIdx.x;
  const int w = tid >> 6, l = tid & 63;
  const int l15 = l & 15, g = l >> 4;
  const long r0 = ((long)blockIdx.x * 4 + w) * 16;

  __shared__ unsigned short TqS[4][16][72];
  __shared__ unsigned short TfS[4][16][136];

  bf16x8 ax[2];
#pragma unroll
  for (int kk = 0; kk < 2; kk++)
    ax[kk] = cvt8(x + (r0 + l15) * 64 + kk * 32 + g * 8);

  proj_chain(ax, Wq, bq, Wmq, bmq, q0w, fqw, TqS[w], TfS[w], r0, l15, g, l);
  proj_chain(ax, Wk, bk, Wmk, bmk, k0w, fkw, TqS[w], TfS[w], r0, l15, g, l);
}

// ---------------------------------------------------------------------------
// Kernel 2 (v2): one wave = 16 q-rows x all 2048 keys. No LDS, no barriers.
// Pass1: fp32 row sums in registers (pred and true), shfl_xor butterfly.
// Pass2: recompute identical tiles, scale by 1/sum, store fp32 directly.
// Grid (x=bh, y=qtile): XCD = linear%8 = bh%8 -> each XCD's L2 holds 4 bh
// of fk+k0 (~3MB <= 4MB), so pass-2 re-reads are L2 hits.
// ---------------------------------------------------------------------------
__global__ __launch_bounds__(256, 4) void k_attn(
    const unsigned short* __restrict__ q0w, const unsigned short* __restrict__ k0w,
    const unsigned short* __restrict__ fqw, const unsigned short* __restrict__ fkw,
    float* __restrict__ out)
{
  const int bh = blockIdx.x;          // 0..31
  const int qt = blockIdx.y;          // 0..31
  const int tid = threadIdx.x;
  const int w = tid >> 6, l = tid & 63;
  const int l15 = l & 15, g = l >> 4;
  const int qrow0 = qt * 64 + w * 16; // this wave's 16 q-rows

  // A-frags for this wave's 16 q-rows
  const unsigned short* fqp = fqw + ((long)bh * NN + qrow0) * 128;
  bf16x8 afq[4];
#pragma unroll
  for (int kk = 0; kk < 4; kk++)
    afq[kk] = *(const bf16x8*)(fqp + l15 * 128 + kk * 32 + g * 8);
  const unsigned short* q0p = q0w + ((long)bh * NN + qrow0) * 64;
  bf16x8 aq0[2];
#pragma unroll
  for (int kk = 0; kk < 2; kk++)
    aq0[kk] = *(const bf16x8*)(q0p + l15 * 64 + kk * 32 + g * 8);

  const unsigned short* fkp = fkw + (long)bh * NN * 128;
  const unsigned short* k0p = k0w + (long)bh * NN * 64;

  // =================== Pass 1: row sums only ===================
  float sp[4] = {0.f, 0.f, 0.f, 0.f};
  float st[4] = {0.f, 0.f, 0.f, 0.f};
  for (int t = 0; t < 128; t++) {
    const unsigned short* bpf = fkp + (t * 16 + l15) * 128 + g * 8;
    const unsigned short* bpk = k0p + (t * 16 + l15) * 64 + g * 8;
    f32x4 accp = {0.f, 0.f, 0.f, 0.f};
    f32x4 acct = {0.f, 0.f, 0.f, 0.f};
#pragma unroll
    for (int kk = 0; kk < 4; kk++)
      accp = mfma16(afq[kk], *(const bf16x8*)(bpf + kk * 32), accp);
#pragma unroll
    for (int kk = 0; kk < 2; kk++)
      acct = mfma16(aq0[kk], *(const bf16x8*)(bpk + kk * 32), acct);
#pragma unroll
    for (int j = 0; j < 4; j++) {
      sp[j] += accp[j];
      st[j] += __expf(acct[j] * 0.125f);
    }
  }
  float ip[4], it[4];
#pragma unroll
  for (int j = 0; j < 4; j++) {
    float vp = sp[j], vt = st[j];
    vp += __shfl_xor(vp, 1, 16);  vt += __shfl_xor(vt, 1, 16);
    vp += __shfl_xor(vp, 2, 16);  vt += __shfl_xor(vt, 2, 16);
    vp += __shfl_xor(vp, 4, 16);  vt += __shfl_xor(vt, 4, 16);
    vp += __shfl_xor(vp, 8, 16);  vt += __shfl_xor(vt, 8, 16);
    ip[j] = 1.0f / vp;
    it[j] = 1.0f / vt;
  }

  // =================== Pass 2: recompute, normalize, stream out ============
  const long ob_p = (long)bh * NN * NN + (long)qrow0 * NN;
  const long ob_t = ob_p + (long)NBH * NN * NN;
  for (int t = 0; t < 128; t++) {
    const unsigned short* bpf = fkp + (t * 16 + l15) * 128 + g * 8;
    const unsigned short* bpk = k0p + (t * 16 + l15) * 64 + g * 8;
    f32x4 accp = {0.f, 0.f, 0.f, 0.f};
    f32x4 acct = {0.f, 0.f, 0.f, 0.f};
#pragma unroll
    for (int kk = 0; kk < 4; kk++)
      accp = mfma16(afq[kk], *(const bf16x8*)(bpf + kk * 32), accp);
#pragma unroll
    for (int kk = 0; kk < 2; kk++)
      acct = mfma16(aq0[kk], *(const bf16x8*)(bpk + kk * 32), acct);
#pragma unroll
    for (int j = 0; j < 4; j++) {
      long o = (long)(g * 4 + j) * NN + t * 16 + l15;
      out[ob_p + o] = accp[j] * ip[j];
      out[ob_t + o] = __expf(acct[j] * 0.125f) * it[j];
    }
  }
}

extern "C" void kernel_launch(void* const* d_in, const int* in_sizes, int n_in,
                              void* d_out, int out_size, void* d_ws, size_t ws_size,
                              hipStream_t stream) {
  const float* x   = (const float*)d_in[0];
  const float* Wq  = (const float*)d_in[1];
  const float* bq  = (const float*)d_in[2];
  const float* Wk  = (const float*)d_in[3];
  const float* bk  = (const float*)d_in[4];
  const float* Wmq = (const float*)d_in[5];
  const float* bmq = (const float*)d_in[6];
  const float* Wmk = (const float*)d_in[7];
  const float* bmk = (const float*)d_in[8];
  float* out = (float*)d_out;

  // ws layout (bf16): q0[32][2048][64], k0[...], fq[32][2048][128], fk[...] = 48 MB
  unsigned short* q0w = (unsigned short*)d_ws;
  unsigned short* k0w = q0w + (long)NBH * NN * 64;
  unsigned short* fqw = k0w + (long)NBH * NN * 64;
  unsigned short* fkw = fqw + (long)NBH * NN * 128;

  hipLaunchKernelGGL(k_proj, dim3(1024), dim3(256), 0, stream,
                     x, Wq, bq, Wk, bk, Wmq, bmq, Wmk, bmk, q0w, k0w, fqw, fkw);
  hipLaunchKernelGGL(k_attn, dim3(NBH, 32), dim3(256), 0, stream,
                     q0w, k0w, fqw, fkw, out);
}

// Round 3
// 626.392 us; speedup vs baseline: 1.4261x; 1.4261x over previous
//
#include <hip/hip_runtime.h>

// ---------------------------------------------------------------------------
// HedgeHog attention distillation map: pred = (fq.fk^T) rownorm, true = softmax(q0.k0^T/8)
// Output [2,2,16,2048,2048] fp32 = 1.07 GiB -> HBM-write-bound (~170us floor).
//
// v3: stores must be contiguous bursts (v2's scattered dwords -> 1.3 TB/s).
//  k_proj:   x->q0,k0->fq,fk (bf16, 48MB ws).
//  k_colsum: Sfk[bh][128] = sum_n fk[n]  (pred rowsum factorization), static global.
//  k_write:  per (bh,16 rows): short true-sum pass (2 MFMA/tile) + pred dot;
//            then stream 256-key chunks: MFMA -> normalize -> LDS transpose ->
//            four 1KB-contiguous dwordx4 stores per wave. ~5 blocks/CU overlap.
// ---------------------------------------------------------------------------

typedef __attribute__((ext_vector_type(8))) short  bf16x8;
typedef __attribute__((ext_vector_type(4))) float  f32x4;

#define NN 2048
#define NBH 32

__device__ float g_Sfk[NBH * 128];   // fk column sums (static: ws stays 48MB)

__device__ __forceinline__ float bf2f(unsigned short u) {
  union { unsigned int i; float f; } v; v.i = ((unsigned int)u) << 16; return v.f;
}
__device__ __forceinline__ unsigned short f2bf(float f) {
  union { float f; unsigned int i; } v; v.f = f;
  unsigned int x = v.i;
  return (unsigned short)((x + 0x7FFFu + ((x >> 16) & 1u)) >> 16);  // RNE
}
__device__ __forceinline__ bf16x8 cvt8(const float* __restrict__ p) {
  bf16x8 v;
#pragma unroll
  for (int i = 0; i < 8; i++) v[i] = (short)f2bf(p[i]);
  return v;
}
__device__ __forceinline__ f32x4 mfma16(bf16x8 a, bf16x8 b, f32x4 c) {
  return __builtin_amdgcn_mfma_f32_16x16x32_bf16(a, b, c, 0, 0, 0);
}

// ---------------------------------------------------------------------------
// Kernel 1: projections + hedgehog features. One wave owns 16 rows.
// ---------------------------------------------------------------------------
__device__ __forceinline__ void proj_chain(
    const bf16x8 ax[2],
    const float* __restrict__ W1, const float* __restrict__ b1,
    const float* __restrict__ W2, const float* __restrict__ b2,
    unsigned short* __restrict__ o1w, unsigned short* __restrict__ o2w,
    unsigned short (*Tq)[72], unsigned short (*Tf)[136],
    long r0, int l15, int g, int l)
{
#pragma unroll
  for (int nt = 0; nt < 4; nt++) {
    f32x4 acc = {0.f, 0.f, 0.f, 0.f};
    acc = mfma16(ax[0], cvt8(W1 + (nt * 16 + l15) * 64 + g * 8), acc);
    acc = mfma16(ax[1], cvt8(W1 + (nt * 16 + l15) * 64 + 32 + g * 8), acc);
    float bv = b1[nt * 16 + l15];
#pragma unroll
    for (int j = 0; j < 4; j++)
      Tq[g * 4 + j][nt * 16 + l15] = f2bf(acc[j] + bv);   // C layout: row=(l>>4)*4+j, col=l&15
  }
#pragma unroll
  for (int i = 0; i < 2; i++) {
    int c = i * 64 + l;
    int r = c >> 3, cc = c & 7;
    *(bf16x8*)(o1w + (r0 + r) * 64 + cc * 8) = *(const bf16x8*)&Tq[r][cc * 8];
  }
  bf16x8 a1[2];
#pragma unroll
  for (int kk = 0; kk < 2; kk++)
    a1[kk] = *(const bf16x8*)&Tq[l15][kk * 32 + g * 8];
#pragma unroll
  for (int nt = 0; nt < 4; nt++) {
    f32x4 acc = {0.f, 0.f, 0.f, 0.f};
    acc = mfma16(a1[0], cvt8(W2 + (nt * 16 + l15) * 64 + g * 8), acc);
    acc = mfma16(a1[1], cvt8(W2 + (nt * 16 + l15) * 64 + 32 + g * 8), acc);
    float bv = b2[nt * 16 + l15];
#pragma unroll
    for (int j = 0; j < 4; j++) {
      float h = acc[j] + bv;
      Tf[g * 4 + j][nt * 16 + l15]      = f2bf(__expf(h));
      Tf[g * 4 + j][64 + nt * 16 + l15] = f2bf(__expf(-h));
    }
  }
#pragma unroll
  for (int i = 0; i < 4; i++) {
    int c = i * 64 + l;
    int r = c >> 4, cc = c & 15;
    *(bf16x8*)(o2w + (r0 + r) * 128 + cc * 8) = *(const bf16x8*)&Tf[r][cc * 8];
  }
}

__global__ __launch_bounds__(256) void k_proj(
    const float* __restrict__ x,
    const float* __restrict__ Wq,  const float* __restrict__ bq,
    const float* __restrict__ Wk,  const float* __restrict__ bk,
    const float* __restrict__ Wmq, const float* __restrict__ bmq,
    const float* __restrict__ Wmk, const float* __restrict__ bmk,
    unsigned short* __restrict__ q0w, unsigned short* __restrict__ k0w,
    unsigned short* __restrict__ fqw, unsigned short* __restrict__ fkw)
{
  const int tid = threadIdx.x;
  const int w = tid >> 6, l = tid & 63;
  const int l15 = l & 15, g = l >> 4;
  const long r0 = ((long)blockIdx.x * 4 + w) * 16;

  __shared__ unsigned short TqS[4][16][72];
  __shared__ unsigned short TfS[4][16][136];

  bf16x8 ax[2];
#pragma unroll
  for (int kk = 0; kk < 2; kk++)
    ax[kk] = cvt8(x + (r0 + l15) * 64 + kk * 32 + g * 8);

  proj_chain(ax, Wq, bq, Wmq, bmq, q0w, fqw, TqS[w], TfS[w], r0, l15, g, l);
  proj_chain(ax, Wk, bk, Wmk, bmk, k0w, fkw, TqS[w], TfS[w], r0, l15, g, l);
}

// ---------------------------------------------------------------------------
// Kernel 2: fk column sums -> g_Sfk[bh][128]
// ---------------------------------------------------------------------------
__global__ __launch_bounds__(256) void k_colsum(const unsigned short* __restrict__ fkw)
{
  const int bh = blockIdx.x;
  const int tid = threadIdx.x;
  const int col = tid & 127, half = tid >> 7;
  const unsigned short* fkp = fkw + (long)bh * NN * 128;
  float acc = 0.f;
#pragma unroll 4
  for (int n = half; n < NN; n += 2)
    acc += bf2f(fkp[(long)n * 128 + col]);
  __shared__ float red[2][128];
  red[half][col] = acc;
  __syncthreads();
  if (tid < 128) g_Sfk[bh * 128 + tid] = red[0][tid] + red[1][tid];
}

// ---------------------------------------------------------------------------
// Kernel 3: per (bh, 16 q-rows): true row-sums (pass 1) + factorized pred
// sums, then stream normalized fp32 in 1KB-contiguous bursts via LDS transpose.
// ---------------------------------------------------------------------------
__global__ __launch_bounds__(256, 4) void k_write(
    const unsigned short* __restrict__ q0w, const unsigned short* __restrict__ k0w,
    const unsigned short* __restrict__ fqw, const unsigned short* __restrict__ fkw,
    float* __restrict__ out)
{
  const int bh = blockIdx.x;          // 0..31
  const int rg = blockIdx.y;          // 0..127
  const int tid = threadIdx.x;
  const int w = tid >> 6, l = tid & 63;
  const int l15 = l & 15, g = l >> 4;
  const int qrow0 = rg * 16;

  __shared__ float buf[16][260];      // 256-col strip, stride 260 (2-way-free banks)
  __shared__ float sred[4][16];

  // ---- A fragments (all 4 waves: same 16 rows) ----
  const unsigned short* fqp = fqw + ((long)bh * NN + qrow0) * 128;
  bf16x8 afq[4];
#pragma unroll
  for (int kk = 0; kk < 4; kk++)
    afq[kk] = *(const bf16x8*)(fqp + l15 * 128 + kk * 32 + g * 8);
  const unsigned short* q0p = q0w + ((long)bh * NN + qrow0) * 64;
  bf16x8 aq0[2];
#pragma unroll
  for (int kk = 0; kk < 2; kk++)
    aq0[kk] = *(const bf16x8*)(q0p + l15 * 64 + kk * 32 + g * 8);

  const unsigned short* fkp = fkw + (long)bh * NN * 128;
  const unsigned short* k0p = k0w + (long)bh * NN * 64;

  // ---- pred reciprocals: ip = 1 / (fq[row] . Sfk)  (factorized row sum) ----
  float dotv = 0.f;
  {
    const unsigned short* p = fqp + (long)l15 * 128 + g * 32;
    const float* sp = g_Sfk + bh * 128 + g * 32;
#pragma unroll
    for (int i = 0; i < 32; i += 8) {
      bf16x8 v = *(const bf16x8*)(p + i);
#pragma unroll
      for (int jj = 0; jj < 8; jj++)
        dotv += bf2f((unsigned short)v[jj]) * sp[i + jj];
    }
  }
  dotv += __shfl_xor(dotv, 16, 64);
  dotv += __shfl_xor(dotv, 32, 64);   // every lane: full dot for row (l&15)
  float ip[4];
#pragma unroll
  for (int j = 0; j < 4; j++)
    ip[j] = 1.0f / __shfl(dotv, (g * 4 + j) & 15, 16);

  // ---- pass 1: true row sums, keys split across waves ----
  float st[4] = {0.f, 0.f, 0.f, 0.f};
  for (int t = w; t < 128; t += 4) {
    const unsigned short* bp = k0p + (long)(t * 16 + l15) * 64 + g * 8;
    f32x4 acc = {0.f, 0.f, 0.f, 0.f};
    acc = mfma16(aq0[0], *(const bf16x8*)bp, acc);
    acc = mfma16(aq0[1], *(const bf16x8*)(bp + 32), acc);
#pragma unroll
    for (int j = 0; j < 4; j++) st[j] += __expf(acc[j] * 0.125f);
  }
#pragma unroll
  for (int j = 0; j < 4; j++) {
    float v = st[j];
    v += __shfl_xor(v, 1, 16);
    v += __shfl_xor(v, 2, 16);
    v += __shfl_xor(v, 4, 16);
    v += __shfl_xor(v, 8, 16);
    if (l15 == 0) sred[w][g * 4 + j] = v;
  }
  __syncthreads();
  float it[4];
#pragma unroll
  for (int j = 0; j < 4; j++)
    it[j] = 1.0f / (sred[0][g * 4 + j] + sred[1][g * 4 + j] +
                    sred[2][g * 4 + j] + sred[3][g * 4 + j]);
  __syncthreads();

  // ---- pass 2: stream 256-key chunks ----
  const long ob_p = (long)bh * NN * NN + (long)qrow0 * NN;
  const long ob_t = ob_p + (long)NBH * NN * NN;

  for (int c = 0; c < 8; c++) {
    const int kc = c * 256;
    // pred compute -> buf (normalized)
#pragma unroll
    for (int tl = 0; tl < 4; tl++) {
      const int kt = kc + w * 64 + tl * 16;
      const unsigned short* bp = fkp + (long)(kt + l15) * 128 + g * 8;
      f32x4 acc = {0.f, 0.f, 0.f, 0.f};
#pragma unroll
      for (int kk = 0; kk < 4; kk++)
        acc = mfma16(afq[kk], *(const bf16x8*)(bp + kk * 32), acc);
      const int col = w * 64 + tl * 16 + l15;
#pragma unroll
      for (int j = 0; j < 4; j++)
        buf[g * 4 + j][col] = acc[j] * ip[j];
    }
    __syncthreads();
    // pred store: wave w -> rows w*4..w*4+3, 1KB contiguous per instr
#pragma unroll
    for (int i = 0; i < 4; i++) {
      const int r = w * 4 + i;
      *(f32x4*)(out + ob_p + (long)r * NN + kc + l * 4) = *(const f32x4*)&buf[r][l * 4];
    }
    __syncthreads();
    // true compute -> buf (normalized)
#pragma unroll
    for (int tl = 0; tl < 4; tl++) {
      const int kt = kc + w * 64 + tl * 16;
      const unsigned short* bp = k0p + (long)(kt + l15) * 64 + g * 8;
      f32x4 acc = {0.f, 0.f, 0.f, 0.f};
      acc = mfma16(aq0[0], *(const bf16x8*)bp, acc);
      acc = mfma16(aq0[1], *(const bf16x8*)(bp + 32), acc);
      const int col = w * 64 + tl * 16 + l15;
#pragma unroll
      for (int j = 0; j < 4; j++)
        buf[g * 4 + j][col] = __expf(acc[j] * 0.125f) * it[j];
    }
    __syncthreads();
    // true store
#pragma unroll
    for (int i = 0; i < 4; i++) {
      const int r = w * 4 + i;
      *(f32x4*)(out + ob_t + (long)r * NN + kc + l * 4) = *(const f32x4*)&buf[r][l * 4];
    }
    __syncthreads();
  }
}

extern "C" void kernel_launch(void* const* d_in, const int* in_sizes, int n_in,
                              void* d_out, int out_size, void* d_ws, size_t ws_size,
                              hipStream_t stream) {
  const float* x   = (const float*)d_in[0];
  const float* Wq  = (const float*)d_in[1];
  const float* bq  = (const float*)d_in[2];
  const float* Wk  = (const float*)d_in[3];
  const float* bk  = (const float*)d_in[4];
  const float* Wmq = (const float*)d_in[5];
  const float* bmq = (const float*)d_in[6];
  const float* Wmk = (const float*)d_in[7];
  const float* bmk = (const float*)d_in[8];
  float* out = (float*)d_out;

  // ws layout (bf16): q0[32][2048][64], k0[...], fq[32][2048][128], fk[...] = 48 MB
  unsigned short* q0w = (unsigned short*)d_ws;
  unsigned short* k0w = q0w + (long)NBH * NN * 64;
  unsigned short* fqw = k0w + (long)NBH * NN * 64;
  unsigned short* fkw = fqw + (long)NBH * NN * 128;

  hipLaunchKernelGGL(k_proj, dim3(1024), dim3(256), 0, stream,
                     x, Wq, bq, Wk, bk, Wmq, bmq, Wmk, bmk, q0w, k0w, fqw, fkw);
  hipLaunchKernelGGL(k_colsum, dim3(NBH), dim3(256), 0, stream, fkw);
  hipLaunchKernelGGL(k_write, dim3(NBH, 128), dim3(256), 0, stream,
                     q0w, k0w, fqw, fkw, out);
}